// Round 1
// baseline (62.974 us; speedup 1.0000x reference)
//
#include <hip/hip_runtime.h>
#include <math.h>

#define NB 4
#define WDIM 128
#define KDIM 256
#define EDIM 256
#define ALPHA_NS 0.2f
#define TK 4

// Kernel A: u[b,k,e] = sum_w v[b,k,w]*W1[e,w];  t[b,k,e] = sum_w v[b,k,w]*W2[e,w] + lin_b[e]
// v[b,k,w] = x[b,w,k].  One block handles (b, k0..k0+3), 256 threads = e index.
__global__ __launch_bounds__(256) void k_ut(const float* __restrict__ x,
                                            const float* __restrict__ lin_w,
                                            const float* __restrict__ lin_b,
                                            float* __restrict__ u_ws,
                                            float* __restrict__ t_ws) {
    __shared__ float vrow[TK][WDIM];
    const int blk = blockIdx.x;
    const int b  = blk / (KDIM / TK);
    const int k0 = (blk % (KDIM / TK)) * TK;
    const int tid = threadIdx.x;

    // stage v rows: x[b, w, k0..k0+3] -> vrow[0..3][w]; k contiguous -> float4
    if (tid < WDIM) {
        float4 vv = *(const float4*)(x + (size_t)b * WDIM * KDIM + (size_t)tid * KDIM + k0);
        vrow[0][tid] = vv.x; vrow[1][tid] = vv.y; vrow[2][tid] = vv.z; vrow[3][tid] = vv.w;
    }
    __syncthreads();

    const int e = tid;
    const float4* wrow = (const float4*)(lin_w + (size_t)e * 2 * WDIM); // row e: [W1(128) | W2(128)]
    float accu[TK], acct[TK];
#pragma unroll
    for (int kk = 0; kk < TK; ++kk) { accu[kk] = 0.f; acct[kk] = 0.f; }

    for (int w4 = 0; w4 < WDIM / 4; ++w4) {
        float4 w1 = wrow[w4];
        float4 w2 = wrow[WDIM / 4 + w4];
#pragma unroll
        for (int kk = 0; kk < TK; ++kk) {
            float v0 = vrow[kk][w4 * 4 + 0];
            float v1 = vrow[kk][w4 * 4 + 1];
            float v2 = vrow[kk][w4 * 4 + 2];
            float v3 = vrow[kk][w4 * 4 + 3];
            accu[kk] += w1.x * v0 + w1.y * v1 + w1.z * v2 + w1.w * v3;
            acct[kk] += w2.x * v0 + w2.y * v1 + w2.z * v2 + w2.w * v3;
        }
    }
    const float lb = lin_b[e];
#pragma unroll
    for (int kk = 0; kk < TK; ++kk) {
        size_t off = ((size_t)b * KDIM + (k0 + kk)) * EDIM + e;
        u_ws[off] = accu[kk];
        t_ws[off] = acct[kk] + lb;
    }
}

// Kernel B: one block per (b,i). Thread j computes e_ij, block softmax, then h.
__global__ __launch_bounds__(256) void k_attn(const float* __restrict__ x,
                                              const float* __restrict__ a_vec,
                                              const float* __restrict__ bias,
                                              const float* __restrict__ u_ws,
                                              const float* __restrict__ t_ws,
                                              float* __restrict__ out) {
    __shared__ float u_i[EDIM];
    __shared__ float a_s[EDIM];
    __shared__ float attn[KDIM];
    __shared__ float red[4];

    const int b = blockIdx.x / KDIM;
    const int i = blockIdx.x % KDIM;
    const int tid = threadIdx.x;

    u_i[tid] = u_ws[((size_t)b * KDIM + i) * EDIM + tid];
    a_s[tid] = a_vec[tid];
    __syncthreads();

    const int j = tid;
    const float4* trow = (const float4*)(t_ws + ((size_t)b * KDIM + j) * EDIM);
    const float4* u4 = (const float4*)u_i;
    const float4* a4 = (const float4*)a_s;

    float acc = 0.f;
    for (int e4 = 0; e4 < EDIM / 4; ++e4) {
        float4 tt = trow[e4];
        float4 uu = u4[e4];
        float4 aa = a4[e4];
        float p;
        p = uu.x + tt.x; acc += aa.x * (p > 0.f ? p : ALPHA_NS * p);
        p = uu.y + tt.y; acc += aa.y * (p > 0.f ? p : ALPHA_NS * p);
        p = uu.z + tt.z; acc += aa.z * (p > 0.f ? p : ALPHA_NS * p);
        p = uu.w + tt.w; acc += aa.w * (p > 0.f ? p : ALPHA_NS * p);
    }
    float e_ij = acc + bias[(size_t)i * KDIM + j];

    // block-wide max (4 waves of 64)
    float m = e_ij;
#pragma unroll
    for (int off = 32; off > 0; off >>= 1) m = fmaxf(m, __shfl_xor(m, off, 64));
    const int wave = tid >> 6;
    if ((tid & 63) == 0) red[wave] = m;
    __syncthreads();
    m = fmaxf(fmaxf(red[0], red[1]), fmaxf(red[2], red[3]));

    float p = expf(e_ij - m);
    float s = p;
#pragma unroll
    for (int off = 32; off > 0; off >>= 1) s += __shfl_xor(s, off, 64);
    __syncthreads();   // protect red[] before overwrite
    if ((tid & 63) == 0) red[wave] = s;
    __syncthreads();
    s = red[0] + red[1] + red[2] + red[3];

    attn[j] = p / s;
    __syncthreads();

    // h[b,i,w] = sigmoid(sum_j attn[j] * x[b,w,j]); 2 threads per w (halves of j)
    const int w = tid >> 1;
    const int half = tid & 1;
    const float4* xrow = (const float4*)(x + (size_t)b * WDIM * KDIM + (size_t)w * KDIM + half * 128);
    const float4* at4 = (const float4*)(attn + half * 128);
    float hs = 0.f;
    for (int j4 = 0; j4 < 32; ++j4) {
        float4 xx = xrow[j4];
        float4 at = at4[j4];
        hs += at.x * xx.x + at.y * xx.y + at.z * xx.z + at.w * xx.w;
    }
    hs += __shfl_xor(hs, 1, 64);
    if (half == 0) {
        out[(size_t)b * WDIM * KDIM + (size_t)w * KDIM + i] = 1.f / (1.f + expf(-hs));
    }
}

extern "C" void kernel_launch(void* const* d_in, const int* in_sizes, int n_in,
                              void* d_out, int out_size, void* d_ws, size_t ws_size,
                              hipStream_t stream) {
    const float* x     = (const float*)d_in[0];
    const float* lin_w = (const float*)d_in[1];
    const float* lin_b = (const float*)d_in[2];
    const float* a_vec = (const float*)d_in[3];
    const float* bias  = (const float*)d_in[4];
    float* out = (float*)d_out;

    float* u_ws = (float*)d_ws;
    float* t_ws = u_ws + (size_t)NB * KDIM * EDIM;

    k_ut<<<NB * (KDIM / TK), 256, 0, stream>>>(x, lin_w, lin_b, u_ws, t_ws);
    k_attn<<<NB * KDIM, 256, 0, stream>>>(x, a_vec, bias, u_ws, t_ws, out);
}